// Round 7
// baseline (296.744 us; speedup 1.0000x reference)
//
#include <hip/hip_runtime.h>
#include <hip/hip_bf16.h>
#include <cstdint>
#include <cstddef>

#define N_TOK 4096
#define DM    1024
#define DH    2048
#define NE    8
#define TBM   256            // tile rows for both gemms
#define BN1   256            // gemm1 tile cols
#define BN2   128            // gemm2 tile cols
#define BK    64
#define MAXT  40             // max row-tiles (<= 32 full + 8 partial)
#define HROWS (MAXT * TBM)

typedef unsigned short u16t;
typedef __attribute__((ext_vector_type(4))) float          f32x4;
typedef __attribute__((ext_vector_type(8))) unsigned short u16x8;

__device__ __forceinline__ u16t f2b(float f) {
  union { float f; unsigned u; } v; v.f = f;
  return (u16t)((v.u + 0x7FFFu + ((v.u >> 16) & 1u)) >> 16);
}

__device__ __forceinline__ void gload16(const void* g, void* l) {
  auto gp = (const __attribute__((address_space(1))) unsigned int*)(uintptr_t)g;
  auto lp = (__attribute__((address_space(3))) unsigned int*)(uintptr_t)l;
  __builtin_amdgcn_global_load_lds(gp, lp, 16, 0, 0);
}

__device__ __forceinline__ void mfma16(f32x4& c, u16x8 a, u16x8 b) {
  asm("v_mfma_f32_16x16x32_bf16 %0, %1, %2, %0" : "+v"(c) : "v"(a), "v"(b));
}

__device__ __forceinline__ void barrier_raw() {
  asm volatile("s_barrier" ::: "memory");
}

// ---------------- x -> bf16 ----------------
__global__ void k_cvt_x(const float* __restrict__ x, u16t* __restrict__ x16) {
  int i = blockIdx.x * blockDim.x + threadIdx.x;
  float4 v = reinterpret_cast<const float4*>(x)[i];
  ushort4 o;
  o.x = f2b(v.x); o.y = f2b(v.y); o.z = f2b(v.z); o.w = f2b(v.w);
  reinterpret_cast<ushort4*>(x16)[i] = o;
}

// ---------------- transpose + convert: src[e][R][C] -> dst[e][C][R] ----------------
__global__ void k_tr_cvt(const float* __restrict__ src, u16t* __restrict__ dst, int R, int C) {
  __shared__ float t[64][65];
  const float* s = src + (size_t)blockIdx.z * R * C;
  u16t* d = dst + (size_t)blockIdx.z * R * C;
  int r0 = blockIdx.y * 64, c0 = blockIdx.x * 64;
#pragma unroll
  for (int i = 0; i < 16; ++i) {
    int idx = i * 256 + threadIdx.x;
    int r = idx >> 6, c = idx & 63;
    t[r][c] = s[(size_t)(r0 + r) * C + (c0 + c)];
  }
  __syncthreads();
#pragma unroll
  for (int i = 0; i < 16; ++i) {
    int idx = i * 256 + threadIdx.x;
    int rr = idx >> 6, cc = idx & 63;
    d[(size_t)(c0 + rr) * R + (r0 + cc)] = f2b(t[cc][rr]);
  }
}

// ---------------- gating: fp32 logits, softmax, top-2 (NO atomics) ----------------
__global__ void __launch_bounds__(256) k_gate(const float* __restrict__ x,
                                              const float* __restrict__ gw,
                                              int* __restrict__ topi,
                                              float* __restrict__ topg) {
  __shared__ float gws[NE * DM];
  int tid = threadIdx.x;
#pragma unroll
  for (int i = 0; i < NE * DM / 256; ++i) gws[i * 256 + tid] = gw[i * 256 + tid];
  __syncthreads();
  int wv = tid >> 6, lane = tid & 63;
  int t = blockIdx.x * 4 + wv;
  float acc[NE];
#pragma unroll
  for (int e = 0; e < NE; ++e) acc[e] = 0.f;
  const float* xr = x + (size_t)t * DM;
#pragma unroll
  for (int c = 0; c < DM / 64; ++c) {
    float xv = xr[c * 64 + lane];
#pragma unroll
    for (int e = 0; e < NE; ++e) acc[e] += xv * gws[e * DM + c * 64 + lane];
  }
#pragma unroll
  for (int e = 0; e < NE; ++e) {
#pragma unroll
    for (int m = 1; m < 64; m <<= 1) acc[e] += __shfl_xor(acc[e], m);
  }
  float mx = acc[0];
#pragma unroll
  for (int e = 1; e < NE; ++e) mx = fmaxf(mx, acc[e]);
  float p[NE], s = 0.f;
#pragma unroll
  for (int e = 0; e < NE; ++e) { p[e] = expf(acc[e] - mx); s += p[e]; }
  float inv = 1.f / s;
#pragma unroll
  for (int e = 0; e < NE; ++e) p[e] *= inv;
  int i1 = 0; float g1 = p[0];
#pragma unroll
  for (int e = 1; e < NE; ++e) if (p[e] > g1) { g1 = p[e]; i1 = e; }
  int i2 = -1; float g2 = -1.f;
#pragma unroll
  for (int e = 0; e < NE; ++e) if (e != i1 && p[e] > g2) { g2 = p[e]; i2 = e; }
  if (lane == 0) {
    topi[t * 2 + 0] = i1; topi[t * 2 + 1] = i2;
    topg[t * 2 + 0] = g1; topg[t * 2 + 1] = g2;
  }
}

// ------- merged histogram + scan + tile table (tiles of TBM rows) -------
__global__ void __launch_bounds__(1024) k_scan(const int* __restrict__ topi,
                                               int* __restrict__ offe,
                                               int* __restrict__ cur64,
                                               int* __restrict__ te,
                                               int* __restrict__ trs,
                                               int* __restrict__ tnr,
                                               int* __restrict__ ntiles) {
  __shared__ int hist[NE];
  int tid = threadIdx.x;
  if (tid < NE) { hist[tid] = 0; cur64[tid * 16] = 0; }
  __syncthreads();
  int lc[NE];
#pragma unroll
  for (int e = 0; e < NE; ++e) lc[e] = 0;
#pragma unroll
  for (int i = 0; i < (N_TOK * 2) / 1024; ++i) {
    int v = topi[tid * ((N_TOK * 2) / 1024) + i];
#pragma unroll
    for (int e = 0; e < NE; ++e) lc[e] += (v == e);
  }
#pragma unroll
  for (int e = 0; e < NE; ++e) {
#pragma unroll
    for (int m = 1; m < 64; m <<= 1) lc[e] += __shfl_xor(lc[e], m);
  }
  if ((tid & 63) == 0) {
#pragma unroll
    for (int e = 0; e < NE; ++e) atomicAdd(&hist[e], lc[e]);
  }
  __syncthreads();
  if (tid == 0) {
    int off = 0, nt = 0;
    for (int e = 0; e < NE; ++e) {
      offe[e] = off;
      int c = hist[e];
      for (int i = 0; i < c; i += TBM) {
        te[nt] = e; trs[nt] = off + i; tnr[nt] = min(TBM, c - i); ++nt;
      }
      off += c;
    }
    *ntiles = nt;
  }
}

// ------- scatter with wave-aggregated atomics, padded counters -------
__global__ void k_scatter(const int* __restrict__ topi, const int* __restrict__ offe,
                          int* __restrict__ cur64, int* __restrict__ pair) {
  int t = blockIdx.x * blockDim.x + threadIdx.x;
  int lane = threadIdx.x & 63;
#pragma unroll
  for (int s = 0; s < 2; ++s) {
    int e = topi[t * 2 + s];
    int pos = 0;
#pragma unroll
    for (int ee = 0; ee < NE; ++ee) {
      unsigned long long mask = __ballot(e == ee);
      if (e == ee) {
        int rank = __popcll(mask & ((1ull << lane) - 1ull));
        int leader = __ffsll((long long)mask) - 1;
        int base = 0;
        if (lane == leader) base = atomicAdd(&cur64[ee * 16], (int)__popcll(mask));
        base = __shfl(base, leader);
        pos = offe[ee] + base + rank;
      }
    }
    pair[pos] = t * 2 + s;
  }
}

// ---- GEMM1: 256x256, 8 waves (2Mx4N), counted-vmcnt dbuf, XCD-chunked blocks ----
// 1D grid of 320: xcd=id&7, elem=id>>3; ty = xcd*5 + elem%5 (XCD owns 5
// contiguous row-tiles -> A + one expert's B panel stay in its L2), n0b=elem/5.
__global__ void __launch_bounds__(512, 1) k_gemm1(
    const u16t* __restrict__ x16, const u16t* __restrict__ w1t,
    const float* __restrict__ b1, u16t* __restrict__ h16,
    const int* __restrict__ pair, const int* __restrict__ te,
    const int* __restrict__ trs, const int* __restrict__ tnr,
    const int* __restrict__ ntiles) {
  int b = blockIdx.x;
  int xcd = b & 7, elem = b >> 3;
  int ty = xcd * 5 + (elem % 5);
  int n0 = (elem / 5) * BN1;
  if (ty >= *ntiles) return;
  int e = te[ty], rs = trs[ty], nr = tnr[ty];
  __shared__ u16t As[2][TBM * BK];
  __shared__ u16t Bs[2][BN1 * BK];
  __shared__ int tok[TBM];
  int tid = threadIdx.x;
  if (tid < TBM) {
    int p = rs + (tid < nr ? tid : nr - 1);
    tok[tid] = pair[p] >> 1;
  }
  __syncthreads();
  const u16t* aptr[4]; const u16t* bptr[4];
#pragma unroll
  for (int it = 0; it < 4; ++it) {
    int idx = it * 512 + tid;
    int r = idx >> 3, c = idx & 7;
    int cs = c ^ (r & 7);
    aptr[it] = x16 + (size_t)tok[r] * DM + cs * 8;
    bptr[it] = w1t + (size_t)e * DH * DM + (size_t)(n0 + r) * DM + cs * 8;
  }
  f32x4 acc[8][4];
#pragma unroll
  for (int m = 0; m < 8; ++m)
#pragma unroll
    for (int n = 0; n < 4; ++n) acc[m][n] = {0.f, 0.f, 0.f, 0.f};
  int lane = tid & 63, wv = tid >> 6;
  int wm = wv >> 2, wn = wv & 3;
  int wrO = wm * 128, wcO = wn * 64;
  // prologue: stage tile 0 (8 loads/thread in flight)
#pragma unroll
  for (int it = 0; it < 4; ++it) {
    int idx = it * 512 + tid;
    gload16(aptr[it], &As[0][idx * 8]);
    gload16(bptr[it], &Bs[0][idx * 8]);
  }
  const int NK = DM / BK;
  for (int ks = 0; ks < NK; ++ks) {
    int cur = ks & 1;
    if (ks + 1 < NK) {
      int k1 = (ks + 1) * BK;
#pragma unroll
      for (int it = 0; it < 4; ++it) {
        int idx = it * 512 + tid;
        gload16(aptr[it] + k1, &As[cur ^ 1][idx * 8]);
        gload16(bptr[it] + k1, &Bs[cur ^ 1][idx * 8]);
      }
      asm volatile("s_waitcnt vmcnt(8)" ::: "memory");   // tile k landed, k+1 in flight
    } else {
      asm volatile("s_waitcnt vmcnt(0)" ::: "memory");
    }
    barrier_raw();
    __builtin_amdgcn_s_setprio(1);
#pragma unroll
    for (int kk = 0; kk < 2; ++kk) {
      u16x8 bf[4];
#pragma unroll
      for (int n = 0; n < 4; ++n) {
        int row = wcO + n * 16 + (lane & 15);
        int cs = (kk * 4 + (lane >> 4)) ^ (row & 7);
        bf[n] = *reinterpret_cast<const u16x8*>(&Bs[cur][row * BK + cs * 8]);
      }
#pragma unroll
      for (int m = 0; m < 8; ++m) {
        int row = wrO + m * 16 + (lane & 15);
        int cs = (kk * 4 + (lane >> 4)) ^ (row & 7);
        u16x8 af = *reinterpret_cast<const u16x8*>(&As[cur][row * BK + cs * 8]);
#pragma unroll
        for (int n = 0; n < 4; ++n) mfma16(acc[m][n], af, bf[n]);
      }
    }
    __builtin_amdgcn_s_setprio(0);
    asm volatile("s_waitcnt lgkmcnt(0)" ::: "memory");
    __builtin_amdgcn_sched_barrier(0);
    barrier_raw();
  }
#pragma unroll
  for (int n = 0; n < 4; ++n) {
    int col = n0 + wcO + n * 16 + (lane & 15);
    float bias = b1[e * DH + col];
#pragma unroll
    for (int m = 0; m < 8; ++m) {
#pragma unroll
      for (int r = 0; r < 4; ++r) {
        int rl = wrO + m * 16 + ((lane >> 4) << 2) + r;
        if (rl < nr) {
          float z = acc[m][n][r] + bias;
          float g = 0.5f * z * (1.0f + erff(z * 0.70710678118654752440f));
          h16[(size_t)(rs + rl) * DH + col] = f2b(g);
        }
      }
    }
  }
}

// ---- GEMM2: 256x128, 8 waves (4Mx2N), counted-vmcnt dbuf, XCD-chunked blocks ----
__global__ void __launch_bounds__(512, 1) k_gemm2(
    const u16t* __restrict__ h16, const u16t* __restrict__ w2t,
    const float* __restrict__ b2, float* __restrict__ out,
    const int* __restrict__ pair, const float* __restrict__ topg,
    const int* __restrict__ te, const int* __restrict__ trs,
    const int* __restrict__ tnr, const int* __restrict__ ntiles) {
  int b = blockIdx.x;
  int xcd = b & 7, elem = b >> 3;
  int ty = xcd * 5 + (elem % 5);
  int n0 = (elem / 5) * BN2;
  if (ty >= *ntiles) return;
  int e = te[ty], rs = trs[ty], nr = tnr[ty];
  __shared__ u16t As[2][TBM * BK];
  __shared__ u16t Bs[2][BN2 * BK];
  __shared__ int tsl[TBM];
  __shared__ float gl[TBM];
  int tid = threadIdx.x;
  if (tid < TBM) {
    int p = rs + (tid < nr ? tid : nr - 1);
    int ts = pair[p];
    tsl[tid] = ts;
    gl[tid] = topg[ts];
  }
  __syncthreads();
  const u16t* aptr[4]; const u16t* bptr[2];
#pragma unroll
  for (int it = 0; it < 4; ++it) {
    int idx = it * 512 + tid;
    int r = idx >> 3, c = idx & 7;
    int cs = c ^ (r & 7);
    aptr[it] = h16 + (size_t)(rs + r) * DH + cs * 8;
  }
#pragma unroll
  for (int it = 0; it < 2; ++it) {
    int idx = it * 512 + tid;
    int r = idx >> 3, c = idx & 7;
    int cs = c ^ (r & 7);
    bptr[it] = w2t + (size_t)e * DM * DH + (size_t)(n0 + r) * DH + cs * 8;
  }
  f32x4 acc[4][4];
#pragma unroll
  for (int m = 0; m < 4; ++m)
#pragma unroll
    for (int n = 0; n < 4; ++n) acc[m][n] = {0.f, 0.f, 0.f, 0.f};
  int lane = tid & 63, wv = tid >> 6;
  int wm = wv >> 1, wn = wv & 1;
  int wrO = wm * 64, wcO = wn * 64;
#pragma unroll
  for (int it = 0; it < 4; ++it) {
    int idx = it * 512 + tid;
    gload16(aptr[it], &As[0][idx * 8]);
  }
#pragma unroll
  for (int it = 0; it < 2; ++it) {
    int idx = it * 512 + tid;
    gload16(bptr[it], &Bs[0][idx * 8]);
  }
  const int NK = DH / BK;
  for (int ks = 0; ks < NK; ++ks) {
    int cur = ks & 1;
    if (ks + 1 < NK) {
      int k1 = (ks + 1) * BK;
#pragma unroll
      for (int it = 0; it < 4; ++it) {
        int idx = it * 512 + tid;
        gload16(aptr[it] + k1, &As[cur ^ 1][idx * 8]);
      }
#pragma unroll
      for (int it = 0; it < 2; ++it) {
        int idx = it * 512 + tid;
        gload16(bptr[it] + k1, &Bs[cur ^ 1][idx * 8]);
      }
      asm volatile("s_waitcnt vmcnt(6)" ::: "memory");   // 6 loads/step in flight
    } else {
      asm volatile("s_waitcnt vmcnt(0)" ::: "memory");
    }
    barrier_raw();
    __builtin_amdgcn_s_setprio(1);
#pragma unroll
    for (int kk = 0; kk < 2; ++kk) {
      u16x8 bf[4];
#pragma unroll
      for (int n = 0; n < 4; ++n) {
        int row = wcO + n * 16 + (lane & 15);
        int cs = (kk * 4 + (lane >> 4)) ^ (row & 7);
        bf[n] = *reinterpret_cast<const u16x8*>(&Bs[cur][row * BK + cs * 8]);
      }
#pragma unroll
      for (int m = 0; m < 4; ++m) {
        int row = wrO + m * 16 + (lane & 15);
        int cs = (kk * 4 + (lane >> 4)) ^ (row & 7);
        u16x8 af = *reinterpret_cast<const u16x8*>(&As[cur][row * BK + cs * 8]);
#pragma unroll
        for (int n = 0; n < 4; ++n) mfma16(acc[m][n], af, bf[n]);
      }
    }
    __builtin_amdgcn_s_setprio(0);
    asm volatile("s_waitcnt lgkmcnt(0)" ::: "memory");
    __builtin_amdgcn_sched_barrier(0);
    barrier_raw();
  }
  float bias[4];
#pragma unroll
  for (int n = 0; n < 4; ++n) bias[n] = b2[e * DM + n0 + wcO + n * 16 + (lane & 15)];
#pragma unroll
  for (int m = 0; m < 4; ++m) {
#pragma unroll
    for (int r = 0; r < 4; ++r) {
      int rl = wrO + m * 16 + ((lane >> 4) << 2) + r;
      if (rl < nr) {
        int ts = tsl[rl];
        float g = gl[rl];
        float* orow = out + (size_t)(ts >> 1) * DM;
#pragma unroll
        for (int n = 0; n < 4; ++n) {
          int col = n0 + wcO + n * 16 + (lane & 15);
          float v = g * (acc[m][n][r] + bias[n]);
          unsafeAtomicAdd(&orow[col], v);
        }
      }
    }
  }
}

extern "C" void kernel_launch(void* const* d_in, const int* in_sizes, int n_in,
                              void* d_out, int out_size, void* d_ws, size_t ws_size,
                              hipStream_t stream) {
  const float* x  = (const float*)d_in[0];
  const float* gw = (const float*)d_in[1];
  const float* w1 = (const float*)d_in[2];
  const float* b1 = (const float*)d_in[3];
  const float* w2 = (const float*)d_in[4];
  const float* b2 = (const float*)d_in[5];
  float* out = (float*)d_out;
  char* ws = (char*)d_ws;

  size_t o = 0;
  auto alloc = [&](size_t b) { size_t p = o; o += (b + 255) & ~(size_t)255; return p; };
  size_t X16  = alloc((size_t)N_TOK * DM * 2);
  size_t W1T  = alloc((size_t)NE * DH * DM * 2);
  size_t W2T  = alloc((size_t)NE * DM * DH * 2);
  size_t HB   = alloc((size_t)HROWS * DH * 2);
  size_t TOPI = alloc((size_t)N_TOK * 2 * 4);
  size_t TOPG = alloc((size_t)N_TOK * 2 * 4);
  size_t PAIR = alloc((size_t)HROWS * 4);
  size_t CUR  = alloc(NE * 64);
  size_t OFE  = alloc(64);
  size_t TE   = alloc(MAXT * 4);
  size_t TRS  = alloc(MAXT * 4);
  size_t TNR  = alloc(MAXT * 4);
  size_t NT   = alloc(64);
  (void)ws_size; (void)in_sizes; (void)n_in;

  hipMemsetAsync(out, 0, (size_t)out_size * 4, stream);

  k_cvt_x<<<N_TOK * DM / 1024, 256, 0, stream>>>(x, (u16t*)(ws + X16));
  k_tr_cvt<<<dim3(DH / 64, DM / 64, NE), 256, 0, stream>>>(w1, (u16t*)(ws + W1T), DM, DH);
  k_tr_cvt<<<dim3(DM / 64, DH / 64, NE), 256, 0, stream>>>(w2, (u16t*)(ws + W2T), DH, DM);
  k_gate<<<N_TOK / 4, 256, 0, stream>>>(x, gw, (int*)(ws + TOPI), (float*)(ws + TOPG));
  k_scan<<<1, 1024, 0, stream>>>((int*)(ws + TOPI), (int*)(ws + OFE), (int*)(ws + CUR),
                                 (int*)(ws + TE), (int*)(ws + TRS), (int*)(ws + TNR),
                                 (int*)(ws + NT));
  k_scatter<<<N_TOK / 256, 256, 0, stream>>>((int*)(ws + TOPI), (int*)(ws + OFE),
                                             (int*)(ws + CUR), (int*)(ws + PAIR));
  k_gemm1<<<8 * MAXT, 512, 0, stream>>>(
      (const u16t*)(ws + X16), (const u16t*)(ws + W1T), b1, (u16t*)(ws + HB),
      (const int*)(ws + PAIR), (const int*)(ws + TE), (const int*)(ws + TRS),
      (const int*)(ws + TNR), (const int*)(ws + NT));
  k_gemm2<<<8 * MAXT, 512, 0, stream>>>(
      (const u16t*)(ws + HB), (const u16t*)(ws + W2T), b2, out,
      (const int*)(ws + PAIR), (const float*)(ws + TOPG), (const int*)(ws + TE),
      (const int*)(ws + TRS), (const int*)(ws + TNR), (const int*)(ws + NT));
}

// Round 8
// 285.327 us; speedup vs baseline: 1.0400x; 1.0400x over previous
//
#include <hip/hip_runtime.h>
#include <hip/hip_bf16.h>
#include <cstdint>
#include <cstddef>

#define N_TOK 4096
#define DM    1024
#define DH    2048
#define NE    8
#define TBM   256
#define BN1   256
#define BN2   128
#define BK    64
#define MAXT  40
#define HROWS (MAXT * TBM)

typedef unsigned short u16t;
typedef __attribute__((ext_vector_type(4))) float          f32x4;
typedef __attribute__((ext_vector_type(8))) unsigned short u16x8;

__device__ __forceinline__ u16t f2b(float f) {
  union { float f; unsigned u; } v; v.f = f;
  return (u16t)((v.u + 0x7FFFu + ((v.u >> 16) & 1u)) >> 16);
}

__device__ __forceinline__ void gload16(const void* g, void* l) {
  auto gp = (const __attribute__((address_space(1))) unsigned int*)(uintptr_t)g;
  auto lp = (__attribute__((address_space(3))) unsigned int*)(uintptr_t)l;
  __builtin_amdgcn_global_load_lds(gp, lp, 16, 0, 0);
}

__device__ __forceinline__ void mfma16(f32x4& c, u16x8 a, u16x8 b) {
  asm("v_mfma_f32_16x16x32_bf16 %0, %1, %2, %0" : "+v"(c) : "v"(a), "v"(b));
}

// ---------------- x -> bf16 ----------------
__global__ void k_cvt_x(const float* __restrict__ x, u16t* __restrict__ x16) {
  int i = blockIdx.x * blockDim.x + threadIdx.x;
  float4 v = reinterpret_cast<const float4*>(x)[i];
  ushort4 o;
  o.x = f2b(v.x); o.y = f2b(v.y); o.z = f2b(v.z); o.w = f2b(v.w);
  reinterpret_cast<ushort4*>(x16)[i] = o;
}

// ---------------- transpose + convert ----------------
__global__ void k_tr_cvt(const float* __restrict__ src, u16t* __restrict__ dst, int R, int C) {
  __shared__ float t[64][65];
  const float* s = src + (size_t)blockIdx.z * R * C;
  u16t* d = dst + (size_t)blockIdx.z * R * C;
  int r0 = blockIdx.y * 64, c0 = blockIdx.x * 64;
#pragma unroll
  for (int i = 0; i < 16; ++i) {
    int idx = i * 256 + threadIdx.x;
    int r = idx >> 6, c = idx & 63;
    t[r][c] = s[(size_t)(r0 + r) * C + (c0 + c)];
  }
  __syncthreads();
#pragma unroll
  for (int i = 0; i < 16; ++i) {
    int idx = i * 256 + threadIdx.x;
    int rr = idx >> 6, cc = idx & 63;
    d[(size_t)(c0 + rr) * R + (r0 + cc)] = f2b(t[cc][rr]);
  }
}

// ---------------- gating ----------------
__global__ void __launch_bounds__(256) k_gate(const float* __restrict__ x,
                                              const float* __restrict__ gw,
                                              int* __restrict__ topi,
                                              float* __restrict__ topg) {
  __shared__ float gws[NE * DM];
  int tid = threadIdx.x;
#pragma unroll
  for (int i = 0; i < NE * DM / 256; ++i) gws[i * 256 + tid] = gw[i * 256 + tid];
  __syncthreads();
  int wv = tid >> 6, lane = tid & 63;
  int t = blockIdx.x * 4 + wv;
  float acc[NE];
#pragma unroll
  for (int e = 0; e < NE; ++e) acc[e] = 0.f;
  const float* xr = x + (size_t)t * DM;
#pragma unroll
  for (int c = 0; c < DM / 64; ++c) {
    float xv = xr[c * 64 + lane];
#pragma unroll
    for (int e = 0; e < NE; ++e) acc[e] += xv * gws[e * DM + c * 64 + lane];
  }
#pragma unroll
  for (int e = 0; e < NE; ++e) {
#pragma unroll
    for (int m = 1; m < 64; m <<= 1) acc[e] += __shfl_xor(acc[e], m);
  }
  float mx = acc[0];
#pragma unroll
  for (int e = 1; e < NE; ++e) mx = fmaxf(mx, acc[e]);
  float p[NE], s = 0.f;
#pragma unroll
  for (int e = 0; e < NE; ++e) { p[e] = expf(acc[e] - mx); s += p[e]; }
  float inv = 1.f / s;
#pragma unroll
  for (int e = 0; e < NE; ++e) p[e] *= inv;
  int i1 = 0; float g1 = p[0];
#pragma unroll
  for (int e = 1; e < NE; ++e) if (p[e] > g1) { g1 = p[e]; i1 = e; }
  int i2 = -1; float g2 = -1.f;
#pragma unroll
  for (int e = 0; e < NE; ++e) if (e != i1 && p[e] > g2) { g2 = p[e]; i2 = e; }
  if (lane == 0) {
    topi[t * 2 + 0] = i1; topi[t * 2 + 1] = i2;
    topg[t * 2 + 0] = g1; topg[t * 2 + 1] = g2;
  }
}

// ------- histogram + scan + tile table -------
__global__ void __launch_bounds__(1024) k_scan(const int* __restrict__ topi,
                                               int* __restrict__ offe,
                                               int* __restrict__ cur64,
                                               int* __restrict__ te,
                                               int* __restrict__ trs,
                                               int* __restrict__ tnr,
                                               int* __restrict__ ntiles) {
  __shared__ int hist[NE];
  int tid = threadIdx.x;
  if (tid < NE) { hist[tid] = 0; cur64[tid * 16] = 0; }
  __syncthreads();
  int lc[NE];
#pragma unroll
  for (int e = 0; e < NE; ++e) lc[e] = 0;
#pragma unroll
  for (int i = 0; i < (N_TOK * 2) / 1024; ++i) {
    int v = topi[tid * ((N_TOK * 2) / 1024) + i];
#pragma unroll
    for (int e = 0; e < NE; ++e) lc[e] += (v == e);
  }
#pragma unroll
  for (int e = 0; e < NE; ++e) {
#pragma unroll
    for (int m = 1; m < 64; m <<= 1) lc[e] += __shfl_xor(lc[e], m);
  }
  if ((tid & 63) == 0) {
#pragma unroll
    for (int e = 0; e < NE; ++e) atomicAdd(&hist[e], lc[e]);
  }
  __syncthreads();
  if (tid == 0) {
    int off = 0, nt = 0;
    for (int e = 0; e < NE; ++e) {
      offe[e] = off;
      int c = hist[e];
      for (int i = 0; i < c; i += TBM) {
        te[nt] = e; trs[nt] = off + i; tnr[nt] = min(TBM, c - i); ++nt;
      }
      off += c;
    }
    *ntiles = nt;
  }
}

// ------- scatter -------
__global__ void k_scatter(const int* __restrict__ topi, const int* __restrict__ offe,
                          int* __restrict__ cur64, int* __restrict__ pair) {
  int t = blockIdx.x * blockDim.x + threadIdx.x;
  int lane = threadIdx.x & 63;
#pragma unroll
  for (int s = 0; s < 2; ++s) {
    int e = topi[t * 2 + s];
    int pos = 0;
#pragma unroll
    for (int ee = 0; ee < NE; ++ee) {
      unsigned long long mask = __ballot(e == ee);
      if (e == ee) {
        int rank = __popcll(mask & ((1ull << lane) - 1ull));
        int leader = __ffsll((long long)mask) - 1;
        int base = 0;
        if (lane == leader) base = atomicAdd(&cur64[ee * 16], (int)__popcll(mask));
        base = __shfl(base, leader);
        pos = offe[ee] + base + rank;
      }
    }
    pair[pos] = t * 2 + s;
  }
}

// ==================== GEMM1: 256x256, fine 8-phase, counted vmcnt ====================
// 8 waves 2Mx4N (wave C = 128x64). Per K-tile (BK=64): 4 phases, quadrant (qm,qn)=(p>>1,p&1).
// Halves are quadrant-aligned row sets; stage order per block: A.h0, B.h0, B.h1, A.h1
// (one half per phase), landing in the opposite parity slot. vmcnt steady {4,4,4,4}.
__global__ void __launch_bounds__(512, 1) k_gemm1(
    const u16t* __restrict__ x16, const u16t* __restrict__ w1t,
    const float* __restrict__ b1, u16t* __restrict__ h16,
    const int* __restrict__ pair, const int* __restrict__ te,
    const int* __restrict__ trs, const int* __restrict__ tnr,
    const int* __restrict__ ntiles) {
  int ty = blockIdx.y;
  if (ty >= *ntiles) return;
  int e = te[ty], rs = trs[ty], nr = tnr[ty];
  int n0 = blockIdx.x * BN1;
  __shared__ u16t As[2 * TBM * BK];
  __shared__ u16t Bs[2 * BN1 * BK];
  __shared__ int tok[TBM];
  int tid = threadIdx.x;
  if (tid < TBM) {
    int p = rs + (tid < nr ? tid : nr - 1);
    tok[tid] = pair[p] >> 1;
  }
  __syncthreads();
  int lane = tid & 63, wv = tid >> 6;
  int wm = wv >> 2, wn = wv & 3;          // 2M x 4N
  int hi = lane >> 4, l15 = lane & 15, l7 = lane & 7;
  // staging pointers: A halves h in {0,1}, passes q in {0,1} (64 rows each)
  const u16t* aP[4]; const u16t* bP[4];
  int dstA[4], dstB[4];
#pragma unroll
  for (int h = 0; h < 2; ++h) {
#pragma unroll
    for (int q = 0; q < 2; ++q) {
      int rp = q * 64 + (tid >> 3);                  // 0..127
      int cs = (tid & 7) ^ (rp & 7);
      int growA = (rp & 63) + ((rp >> 6) << 7) + h * 64;
      aP[h * 2 + q] = x16 + (size_t)tok[growA] * DM + cs * 8;
      dstA[h * 2 + q] = (h * 128 + rp) * 64 + (tid & 7) * 8;
      int growB = (rp & 31) + ((rp >> 5) << 6) + h * 32;
      bP[h * 2 + q] = w1t + (size_t)e * DH * DM + (size_t)(n0 + growB) * DM + cs * 8;
      dstB[h * 2 + q] = (h * 128 + rp) * 64 + (tid & 7) * 8;
    }
  }
  f32x4 acc[8][4];
#pragma unroll
  for (int m = 0; m < 8; ++m)
#pragma unroll
    for (int n = 0; n < 4; ++n) acc[m][n] = {0.f, 0.f, 0.f, 0.f};

#define STG_A1(TN, H) { int _pn = (TN) & 1; int _k = (TN) * BK; \
    gload16(aP[(H)*2+0] + _k, &As[_pn * TBM * BK + dstA[(H)*2+0]]); \
    gload16(aP[(H)*2+1] + _k, &As[_pn * TBM * BK + dstA[(H)*2+1]]); }
#define STG_B1(TN, H) { int _pn = (TN) & 1; int _k = (TN) * BK; \
    gload16(bP[(H)*2+0] + _k, &Bs[_pn * BN1 * BK + dstB[(H)*2+0]]); \
    gload16(bP[(H)*2+1] + _k, &Bs[_pn * BN1 * BK + dstB[(H)*2+1]]); }

  // prologue: stage tile 0 in phase order A.h0, B.h0, B.h1, A.h1
  STG_A1(0, 0); STG_B1(0, 0); STG_B1(0, 1); STG_A1(0, 1);

#define PHASE1(QM, QN, VM, STAGE) { \
    asm volatile("s_waitcnt vmcnt(" #VM ")" ::: "memory"); \
    __builtin_amdgcn_s_barrier(); \
    u16x8 af[4][2], bf[2][2]; \
    const u16t* Asp = &As[pi * TBM * BK]; \
    const u16t* Bsp = &Bs[pi * BN1 * BK]; \
    _Pragma("unroll") \
    for (int kk = 0; kk < 2; ++kk) { \
      _Pragma("unroll") \
      for (int mf = 0; mf < 4; ++mf) { \
        int lrow = (QM) * 128 + wm * 64 + mf * 16 + l15; \
        int cs = (kk * 4 + hi) ^ l7; \
        af[mf][kk] = *reinterpret_cast<const u16x8*>(&Asp[lrow * 64 + cs * 8]); \
      } \
      _Pragma("unroll") \
      for (int nf = 0; nf < 2; ++nf) { \
        int lrow = (QN) * 128 + wn * 32 + nf * 16 + l15; \
        int cs = (kk * 4 + hi) ^ l7; \
        bf[nf][kk] = *reinterpret_cast<const u16x8*>(&Bsp[lrow * 64 + cs * 8]); \
      } \
    } \
    STAGE; \
    asm volatile("s_waitcnt lgkmcnt(0)" ::: "memory"); \
    __builtin_amdgcn_sched_barrier(0); \
    __builtin_amdgcn_s_setprio(1); \
    _Pragma("unroll") \
    for (int kk = 0; kk < 2; ++kk) \
      _Pragma("unroll") \
      for (int mf = 0; mf < 4; ++mf) \
        _Pragma("unroll") \
        for (int nf = 0; nf < 2; ++nf) \
          mfma16(acc[(QM) * 4 + mf][(QN) * 2 + nf], af[mf][kk], bf[nf][kk]); \
    __builtin_amdgcn_s_setprio(0); \
    __builtin_amdgcn_s_barrier(); }

  const int NK = DM / BK;                 // 16
  for (int tb = 0; tb < NK - 1; ++tb) {   // steady: stage tile tb+1
    int pi = tb & 1;
    PHASE1(0, 0, 4, STG_A1(tb + 1, 0));
    PHASE1(0, 1, 4, STG_B1(tb + 1, 0));
    PHASE1(1, 0, 4, STG_B1(tb + 1, 1));
    PHASE1(1, 1, 4, STG_A1(tb + 1, 1));
  }
  { // last block: no staging, draining vmcnt {4,2,0,0}
    int pi = (NK - 1) & 1;
    PHASE1(0, 0, 4, );
    PHASE1(0, 1, 2, );
    PHASE1(1, 0, 0, );
    PHASE1(1, 1, 0, );
  }
#undef PHASE1
#undef STG_A1
#undef STG_B1
  int wrO = wm * 128, wcO = wn * 64;
#pragma unroll
  for (int n = 0; n < 4; ++n) {
    int col = n0 + wcO + n * 16 + l15;
    float bias = b1[e * DH + col];
#pragma unroll
    for (int m = 0; m < 8; ++m) {
#pragma unroll
      for (int r = 0; r < 4; ++r) {
        int rl = wrO + m * 16 + (hi << 2) + r;
        if (rl < nr) {
          float z = acc[m][n][r] + bias;
          float g = 0.5f * z * (1.0f + erff(z * 0.70710678118654752440f));
          h16[(size_t)(rs + rl) * DH + col] = f2b(g);
        }
      }
    }
  }
}

// ==================== GEMM2: 256x128, fine 8-phase, counted vmcnt ====================
// 8 waves 2Mx4N (wave C = 128x32, n-frags 2). A halves 2 loads, B halves 1 load.
// Stage order: A.h0(2), B.h0(1), B.h1(1), A.h1(2). vmcnt steady {3,4,3,4}, last {3,2,0,0}.
__global__ void __launch_bounds__(512, 1) k_gemm2(
    const u16t* __restrict__ h16, const u16t* __restrict__ w2t,
    const float* __restrict__ b2, float* __restrict__ out,
    const int* __restrict__ pair, const float* __restrict__ topg,
    const int* __restrict__ te, const int* __restrict__ trs,
    const int* __restrict__ tnr, const int* __restrict__ ntiles) {
  int ty = blockIdx.y;
  if (ty >= *ntiles) return;
  int e = te[ty], rs = trs[ty], nr = tnr[ty];
  int n0 = blockIdx.x * BN2;
  __shared__ u16t As[2 * TBM * BK];
  __shared__ u16t Bs[2 * BN2 * BK];
  __shared__ int tsl[TBM];
  __shared__ float gl[TBM];
  int tid = threadIdx.x;
  if (tid < TBM) {
    int p = rs + (tid < nr ? tid : nr - 1);
    int ts = pair[p];
    tsl[tid] = ts;
    gl[tid] = topg[ts];
  }
  __syncthreads();
  int lane = tid & 63, wv = tid >> 6;
  int wm = wv >> 2, wn = wv & 3;          // 2M x 4N
  int hi = lane >> 4, l15 = lane & 15, l7 = lane & 7;
  const u16t* aP[4]; const u16t* bP[2];
  int dstA[4], dstB[2];
#pragma unroll
  for (int h = 0; h < 2; ++h) {
#pragma unroll
    for (int q = 0; q < 2; ++q) {
      int rp = q * 64 + (tid >> 3);
      int cs = (tid & 7) ^ (rp & 7);
      int growA = (rp & 63) + ((rp >> 6) << 7) + h * 64;
      aP[h * 2 + q] = h16 + (size_t)(rs + growA) * DH + cs * 8;
      dstA[h * 2 + q] = (h * 128 + rp) * 64 + (tid & 7) * 8;
    }
    int rp2 = tid >> 3;                                // 0..63
    int cs2 = (tid & 7) ^ (rp2 & 7);
    int growB = (rp2 & 15) + ((rp2 >> 4) << 5) + h * 16;
    bP[h] = w2t + (size_t)e * DM * DH + (size_t)(n0 + growB) * DH + cs2 * 8;
    dstB[h] = (h * 64 + rp2) * 64 + (tid & 7) * 8;
  }
  f32x4 acc[8][2];
#pragma unroll
  for (int m = 0; m < 8; ++m)
#pragma unroll
    for (int n = 0; n < 2; ++n) acc[m][n] = {0.f, 0.f, 0.f, 0.f};

#define STG_A2(TN, H) { int _pn = (TN) & 1; int _k = (TN) * BK; \
    gload16(aP[(H)*2+0] + _k, &As[_pn * TBM * BK + dstA[(H)*2+0]]); \
    gload16(aP[(H)*2+1] + _k, &As[_pn * TBM * BK + dstA[(H)*2+1]]); }
#define STG_B2(TN, H) { int _pn = (TN) & 1; int _k = (TN) * BK; \
    gload16(bP[(H)] + _k, &Bs[_pn * BN2 * BK + dstB[(H)]]); }

  STG_A2(0, 0); STG_B2(0, 0); STG_B2(0, 1); STG_A2(0, 1);

#define PHASE2(QM, QN, VM, STAGE) { \
    asm volatile("s_waitcnt vmcnt(" #VM ")" ::: "memory"); \
    __builtin_amdgcn_s_barrier(); \
    u16x8 af[4][2], bf[2]; \
    const u16t* Asp = &As[pi * TBM * BK]; \
    const u16t* Bsp = &Bs[pi * BN2 * BK]; \
    _Pragma("unroll") \
    for (int kk = 0; kk < 2; ++kk) { \
      _Pragma("unroll") \
      for (int mf = 0; mf < 4; ++mf) { \
        int lrow = (QM) * 128 + wm * 64 + mf * 16 + l15; \
        int cs = (kk * 4 + hi) ^ l7; \
        af[mf][kk] = *reinterpret_cast<const u16x8*>(&Asp[lrow * 64 + cs * 8]); \
      } \
      { int lrow = (QN) * 64 + wn * 16 + l15; \
        int cs = (kk * 4 + hi) ^ l7; \
        bf[kk] = *reinterpret_cast<const u16x8*>(&Bsp[lrow * 64 + cs * 8]); } \
    } \
    STAGE; \
    asm volatile("s_waitcnt lgkmcnt(0)" ::: "memory"); \
    __builtin_amdgcn_sched_barrier(0); \
    __builtin_amdgcn_s_setprio(1); \
    _Pragma("unroll") \
    for (int kk = 0; kk < 2; ++kk) \
      _Pragma("unroll") \
      for (int mf = 0; mf < 4; ++mf) \
        mfma16(acc[(QM) * 4 + mf][(QN)], af[mf][kk], bf[kk]); \
    __builtin_amdgcn_s_setprio(0); \
    __builtin_amdgcn_s_barrier(); }

  const int NK = DH / BK;                 // 32
  for (int tb = 0; tb < NK - 1; ++tb) {
    int pi = tb & 1;
    PHASE2(0, 0, 3, STG_A2(tb + 1, 0));
    PHASE2(0, 1, 4, STG_B2(tb + 1, 0));
    PHASE2(1, 0, 3, STG_B2(tb + 1, 1));
    PHASE2(1, 1, 4, STG_A2(tb + 1, 1));
  }
  {
    int pi = (NK - 1) & 1;
    PHASE2(0, 0, 3, );
    PHASE2(0, 1, 2, );
    PHASE2(1, 0, 0, );
    PHASE2(1, 1, 0, );
  }
#undef PHASE2
#undef STG_A2
#undef STG_B2
  int wrO = wm * 128, wcO = wn * 32;
  float bias[2];
#pragma unroll
  for (int n = 0; n < 2; ++n) bias[n] = b2[e * DM + n0 + wcO + n * 16 + l15];
#pragma unroll
  for (int m = 0; m < 8; ++m) {
#pragma unroll
    for (int r = 0; r < 4; ++r) {
      int rl = wrO + m * 16 + (hi << 2) + r;
      if (rl < nr) {
        int ts = tsl[rl];
        float g = gl[rl];
        float* orow = out + (size_t)(ts >> 1) * DM;
#pragma unroll
        for (int n = 0; n < 2; ++n) {
          int col = n0 + wcO + n * 16 + l15;
          float v = g * (acc[m][n][r] + bias[n]);
          unsafeAtomicAdd(&orow[col], v);
        }
      }
    }
  }
}

extern "C" void kernel_launch(void* const* d_in, const int* in_sizes, int n_in,
                              void* d_out, int out_size, void* d_ws, size_t ws_size,
                              hipStream_t stream) {
  const float* x  = (const float*)d_in[0];
  const float* gw = (const float*)d_in[1];
  const float* w1 = (const float*)d_in[2];
  const float* b1 = (const float*)d_in[3];
  const float* w2 = (const float*)d_in[4];
  const float* b2 = (const float*)d_in[5];
  float* out = (float*)d_out;
  char* ws = (char*)d_ws;

  size_t o = 0;
  auto alloc = [&](size_t b) { size_t p = o; o += (b + 255) & ~(size_t)255; return p; };
  size_t X16  = alloc((size_t)N_TOK * DM * 2);
  size_t W1T  = alloc((size_t)NE * DH * DM * 2);
  size_t W2T  = alloc((size_t)NE * DM * DH * 2);
  size_t HB   = alloc((size_t)HROWS * DH * 2);
  size_t TOPI = alloc((size_t)N_TOK * 2 * 4);
  size_t TOPG = alloc((size_t)N_TOK * 2 * 4);
  size_t PAIR = alloc((size_t)HROWS * 4);
  size_t CUR  = alloc(NE * 64);
  size_t OFE  = alloc(64);
  size_t TE   = alloc(MAXT * 4);
  size_t TRS  = alloc(MAXT * 4);
  size_t TNR  = alloc(MAXT * 4);
  size_t NT   = alloc(64);
  (void)ws_size; (void)in_sizes; (void)n_in;

  hipMemsetAsync(out, 0, (size_t)out_size * 4, stream);

  k_cvt_x<<<N_TOK * DM / 1024, 256, 0, stream>>>(x, (u16t*)(ws + X16));
  k_tr_cvt<<<dim3(DH / 64, DM / 64, NE), 256, 0, stream>>>(w1, (u16t*)(ws + W1T), DM, DH);
  k_tr_cvt<<<dim3(DM / 64, DH / 64, NE), 256, 0, stream>>>(w2, (u16t*)(ws + W2T), DH, DM);
  k_gate<<<N_TOK / 4, 256, 0, stream>>>(x, gw, (int*)(ws + TOPI), (float*)(ws + TOPG));
  k_scan<<<1, 1024, 0, stream>>>((int*)(ws + TOPI), (int*)(ws + OFE), (int*)(ws + CUR),
                                 (int*)(ws + TE), (int*)(ws + TRS), (int*)(ws + TNR),
                                 (int*)(ws + NT));
  k_scatter<<<N_TOK / 256, 256, 0, stream>>>((int*)(ws + TOPI), (int*)(ws + OFE),
                                             (int*)(ws + CUR), (int*)(ws + PAIR));
  k_gemm1<<<dim3(DH / BN1, MAXT), 512, 0, stream>>>(
      (const u16t*)(ws + X16), (const u16t*)(ws + W1T), b1, (u16t*)(ws + HB),
      (const int*)(ws + PAIR), (const int*)(ws + TE), (const int*)(ws + TRS),
      (const int*)(ws + TNR), (const int*)(ws + NT));
  k_gemm2<<<dim3(DM / BN2, MAXT), 512, 0, stream>>>(
      (const u16t*)(ws + HB), (const u16t*)(ws + W2T), b2, out,
      (const int*)(ws + PAIR), (const float*)(ws + TOPG), (const int*)(ws + TE),
      (const int*)(ws + TRS), (const int*)(ws + TNR), (const int*)(ws + NT));
}

// Round 9
// 210.319 us; speedup vs baseline: 1.4109x; 1.3566x over previous
//
#include <hip/hip_runtime.h>
#include <hip/hip_bf16.h>
#include <cstdint>
#include <cstddef>

#define N_TOK 4096
#define DM    1024
#define DH    2048
#define NE    8
#define BM    128
#define BN    128
#define BK    64
#define MAXT  80
#define HROWS (MAXT * BM)

typedef unsigned short u16t;
typedef __attribute__((ext_vector_type(4))) float          f32x4;
typedef __attribute__((ext_vector_type(8))) unsigned short u16x8;

__device__ __forceinline__ u16t f2b(float f) {
  union { float f; unsigned u; } v; v.f = f;
  return (u16t)((v.u + 0x7FFFu + ((v.u >> 16) & 1u)) >> 16);
}

__device__ __forceinline__ void gload16(const void* g, void* l) {
  auto gp = (const __attribute__((address_space(1))) unsigned int*)(uintptr_t)g;
  auto lp = (__attribute__((address_space(3))) unsigned int*)(uintptr_t)l;
  __builtin_amdgcn_global_load_lds(gp, lp, 16, 0, 0);
}

__device__ __forceinline__ void mfma16(f32x4& c, u16x8 a, u16x8 b) {
  asm("v_mfma_f32_16x16x32_bf16 %0, %1, %2, %0" : "+v"(c) : "v"(a), "v"(b));
}

// ============ fused prologue: tr_cvt(w1) | tr_cvt(w2) | gate(+x->bf16) ============
// blocks [0,4096): w1 transpose-convert; [4096,8192): w2; [8192,9216): gating.
__global__ void __launch_bounds__(256) k_prep(
    const float* __restrict__ x,  const float* __restrict__ gw,
    const float* __restrict__ w1, const float* __restrict__ w2,
    u16t* __restrict__ x16, u16t* __restrict__ w1t, u16t* __restrict__ w2t,
    int* __restrict__ topi, float* __restrict__ topg) {
  __shared__ float smem[NE * DM];          // 32 KB, aliased per path
  int b = blockIdx.x;
  int tid = threadIdx.x;
  if (b < 8192) {
    // -------- transpose + convert: src[e][R][C] -> dst[e][C][R] --------
    const float* src; u16t* dst; int R, C, bx, by, bz;
    if (b < 4096) {                         // w1: R=1024, C=2048 -> 32x16 blocks/expert
      int l = b; bz = l >> 9; int rem = l & 511;
      R = DM; C = DH; bx = rem & 31; by = rem >> 5; src = w1; dst = w1t;
    } else {                                // w2: R=2048, C=1024 -> 16x32 blocks/expert
      int l = b - 4096; bz = l >> 9; int rem = l & 511;
      R = DH; C = DM; bx = rem & 15; by = rem >> 4; src = w2; dst = w2t;
    }
    float (*t)[65] = reinterpret_cast<float(*)[65]>(smem);
    const float* s = src + (size_t)bz * R * C;
    u16t* d = dst + (size_t)bz * R * C;
    int r0 = by * 64, c0 = bx * 64;
#pragma unroll
    for (int i = 0; i < 16; ++i) {
      int idx = i * 256 + tid;
      int r = idx >> 6, c = idx & 63;
      t[r][c] = s[(size_t)(r0 + r) * C + (c0 + c)];
    }
    __syncthreads();
#pragma unroll
    for (int i = 0; i < 16; ++i) {
      int idx = i * 256 + tid;
      int rr = idx >> 6, cc = idx & 63;
      d[(size_t)(c0 + rr) * R + (r0 + cc)] = f2b(t[cc][rr]);
    }
  } else {
    // -------- gating: fp32 logits, softmax, top-2; also writes x16 --------
    float* gws = smem;
#pragma unroll
    for (int i = 0; i < NE * DM / 256; ++i) gws[i * 256 + tid] = gw[i * 256 + tid];
    __syncthreads();
    int wv = tid >> 6, lane = tid & 63;
    int t = (b - 8192) * 4 + wv;
    float acc[NE];
#pragma unroll
    for (int e = 0; e < NE; ++e) acc[e] = 0.f;
    const float* xr = x + (size_t)t * DM;
    u16t* xo = x16 + (size_t)t * DM;
#pragma unroll
    for (int c = 0; c < DM / 64; ++c) {
      float xv = xr[c * 64 + lane];
      xo[c * 64 + lane] = f2b(xv);          // fused x -> bf16
#pragma unroll
      for (int e = 0; e < NE; ++e) acc[e] += xv * gws[e * DM + c * 64 + lane];
    }
#pragma unroll
    for (int e = 0; e < NE; ++e) {
#pragma unroll
      for (int m = 1; m < 64; m <<= 1) acc[e] += __shfl_xor(acc[e], m);
    }
    float mx = acc[0];
#pragma unroll
    for (int e = 1; e < NE; ++e) mx = fmaxf(mx, acc[e]);
    float p[NE], s = 0.f;
#pragma unroll
    for (int e = 0; e < NE; ++e) { p[e] = expf(acc[e] - mx); s += p[e]; }
    float inv = 1.f / s;
#pragma unroll
    for (int e = 0; e < NE; ++e) p[e] *= inv;
    int i1 = 0; float g1 = p[0];
#pragma unroll
    for (int e = 1; e < NE; ++e) if (p[e] > g1) { g1 = p[e]; i1 = e; }
    int i2 = -1; float g2 = -1.f;
#pragma unroll
    for (int e = 0; e < NE; ++e) if (e != i1 && p[e] > g2) { g2 = p[e]; i2 = e; }
    if (lane == 0) {
      topi[t * 2 + 0] = i1; topi[t * 2 + 1] = i2;
      topg[t * 2 + 0] = g1; topg[t * 2 + 1] = g2;
    }
  }
}

// ------- merged histogram + scan + tile table (1 block, 1024 threads) -------
__global__ void __launch_bounds__(1024) k_scan(const int* __restrict__ topi,
                                               int* __restrict__ offe,
                                               int* __restrict__ cur64,
                                               int* __restrict__ te,
                                               int* __restrict__ trs,
                                               int* __restrict__ tnr,
                                               int* __restrict__ ntiles) {
  __shared__ int hist[NE];
  int tid = threadIdx.x;
  if (tid < NE) { hist[tid] = 0; cur64[tid * 16] = 0; }
  __syncthreads();
  int lc[NE];
#pragma unroll
  for (int e = 0; e < NE; ++e) lc[e] = 0;
#pragma unroll
  for (int i = 0; i < (N_TOK * 2) / 1024; ++i) {
    int v = topi[tid * ((N_TOK * 2) / 1024) + i];
#pragma unroll
    for (int e = 0; e < NE; ++e) lc[e] += (v == e);
  }
#pragma unroll
  for (int e = 0; e < NE; ++e) {
#pragma unroll
    for (int m = 1; m < 64; m <<= 1) lc[e] += __shfl_xor(lc[e], m);
  }
  if ((tid & 63) == 0) {
#pragma unroll
    for (int e = 0; e < NE; ++e) atomicAdd(&hist[e], lc[e]);
  }
  __syncthreads();
  if (tid == 0) {
    int off = 0, nt = 0;
    for (int e = 0; e < NE; ++e) {
      offe[e] = off;
      int c = hist[e];
      for (int i = 0; i < c; i += BM) {
        te[nt] = e; trs[nt] = off + i; tnr[nt] = min(BM, c - i); ++nt;
      }
      off += c;
    }
    *ntiles = nt;
  }
}

// ------- scatter with wave-aggregated atomics, padded counters -------
__global__ void k_scatter(const int* __restrict__ topi, const int* __restrict__ offe,
                          int* __restrict__ cur64, int* __restrict__ pair) {
  int t = blockIdx.x * blockDim.x + threadIdx.x;
  int lane = threadIdx.x & 63;
#pragma unroll
  for (int s = 0; s < 2; ++s) {
    int e = topi[t * 2 + s];
    int pos = 0;
#pragma unroll
    for (int ee = 0; ee < NE; ++ee) {
      unsigned long long mask = __ballot(e == ee);
      if (e == ee) {
        int rank = __popcll(mask & ((1ull << lane) - 1ull));
        int leader = __ffsll((long long)mask) - 1;
        int base = 0;
        if (lane == leader) base = atomicAdd(&cur64[ee * 16], (int)__popcll(mask));
        base = __shfl(base, leader);
        pos = offe[ee] + base + rank;
      }
    }
    pair[pos] = t * 2 + s;
  }
}

// ---------------- GEMM1 (R2/R3-exact): h = gelu(x[tok] @ w1[e] + b1[e]) ----------------
__global__ void __launch_bounds__(256, 2) k_gemm1(
    const u16t* __restrict__ x16, const u16t* __restrict__ w1t,
    const float* __restrict__ b1, u16t* __restrict__ h16,
    const int* __restrict__ pair, const int* __restrict__ te,
    const int* __restrict__ trs, const int* __restrict__ tnr,
    const int* __restrict__ ntiles) {
  int ty = blockIdx.y;
  if (ty >= *ntiles) return;
  int e = te[ty], rs = trs[ty], nr = tnr[ty];
  int n0 = blockIdx.x * BN;
  __shared__ u16t As[BM * BK];
  __shared__ u16t Bs[BN * BK];
  __shared__ int tok[BM];
  int tid = threadIdx.x;
  if (tid < BM) {
    int p = rs + (tid < nr ? tid : nr - 1);
    tok[tid] = pair[p] >> 1;
  }
  __syncthreads();
  const u16t* aptr[4]; const u16t* bptr[4];
#pragma unroll
  for (int it = 0; it < 4; ++it) {
    int idx = it * 256 + tid;
    int r = idx >> 3, c = idx & 7;
    int cs = c ^ (r & 7);
    aptr[it] = x16 + (size_t)tok[r] * DM + cs * 8;
    bptr[it] = w1t + (size_t)e * DH * DM + (size_t)(n0 + r) * DM + cs * 8;
  }
  f32x4 acc[4][4];
#pragma unroll
  for (int m = 0; m < 4; ++m)
#pragma unroll
    for (int n = 0; n < 4; ++n) acc[m][n] = {0.f, 0.f, 0.f, 0.f};
  int lane = tid & 63, wv = tid >> 6;
  int wr = (wv >> 1) * 64, wc = (wv & 1) * 64;
  for (int k0 = 0; k0 < DM; k0 += BK) {
#pragma unroll
    for (int it = 0; it < 4; ++it) {
      int idx = it * 256 + tid;
      gload16(aptr[it] + k0, &As[idx * 8]);
      gload16(bptr[it] + k0, &Bs[idx * 8]);
    }
    __syncthreads();
#pragma unroll
    for (int kk = 0; kk < 2; ++kk) {
      u16x8 af[4], bf[4];
#pragma unroll
      for (int m = 0; m < 4; ++m) {
        int row = wr + m * 16 + (lane & 15);
        int cs = (kk * 4 + (lane >> 4)) ^ (row & 7);
        af[m] = *reinterpret_cast<const u16x8*>(&As[row * BK + cs * 8]);
      }
#pragma unroll
      for (int n = 0; n < 4; ++n) {
        int row = wc + n * 16 + (lane & 15);
        int cs = (kk * 4 + (lane >> 4)) ^ (row & 7);
        bf[n] = *reinterpret_cast<const u16x8*>(&Bs[row * BK + cs * 8]);
      }
#pragma unroll
      for (int m = 0; m < 4; ++m)
#pragma unroll
        for (int n = 0; n < 4; ++n) mfma16(acc[m][n], af[m], bf[n]);
    }
    __syncthreads();
  }
#pragma unroll
  for (int n = 0; n < 4; ++n) {
    int col = n0 + wc + n * 16 + (lane & 15);
    float bias = b1[e * DH + col];
#pragma unroll
    for (int m = 0; m < 4; ++m) {
#pragma unroll
      for (int r = 0; r < 4; ++r) {
        int rl = wr + m * 16 + ((lane >> 4) << 2) + r;
        if (rl < nr) {
          float z = acc[m][n][r] + bias;
          float g = 0.5f * z * (1.0f + erff(z * 0.70710678118654752440f));
          h16[(size_t)(rs + rl) * DH + col] = f2b(g);
        }
      }
    }
  }
}

// ---------------- GEMM2 (R2/R3-exact): out += gate * (h @ w2[e] + b2[e]) ----------------
__global__ void __launch_bounds__(256, 2) k_gemm2(
    const u16t* __restrict__ h16, const u16t* __restrict__ w2t,
    const float* __restrict__ b2, float* __restrict__ out,
    const int* __restrict__ pair, const float* __restrict__ topg,
    const int* __restrict__ te, const int* __restrict__ trs,
    const int* __restrict__ tnr, const int* __restrict__ ntiles) {
  int ty = blockIdx.y;
  if (ty >= *ntiles) return;
  int e = te[ty], rs = trs[ty], nr = tnr[ty];
  int n0 = blockIdx.x * BN;
  __shared__ u16t As[BM * BK];
  __shared__ u16t Bs[BN * BK];
  __shared__ int tsl[BM];
  __shared__ float gl[BM];
  int tid = threadIdx.x;
  if (tid < BM) {
    int p = rs + (tid < nr ? tid : nr - 1);
    int ts = pair[p];
    tsl[tid] = ts;
    gl[tid] = topg[ts];
  }
  __syncthreads();
  const u16t* aptr[4]; const u16t* bptr[4];
#pragma unroll
  for (int it = 0; it < 4; ++it) {
    int idx = it * 256 + tid;
    int r = idx >> 3, c = idx & 7;
    int cs = c ^ (r & 7);
    aptr[it] = h16 + (size_t)(rs + r) * DH + cs * 8;
    bptr[it] = w2t + (size_t)e * DM * DH + (size_t)(n0 + r) * DH + cs * 8;
  }
  f32x4 acc[4][4];
#pragma unroll
  for (int m = 0; m < 4; ++m)
#pragma unroll
    for (int n = 0; n < 4; ++n) acc[m][n] = {0.f, 0.f, 0.f, 0.f};
  int lane = tid & 63, wv = tid >> 6;
  int wr = (wv >> 1) * 64, wc = (wv & 1) * 64;
  for (int k0 = 0; k0 < DH; k0 += BK) {
#pragma unroll
    for (int it = 0; it < 4; ++it) {
      int idx = it * 256 + tid;
      gload16(aptr[it] + k0, &As[idx * 8]);
      gload16(bptr[it] + k0, &Bs[idx * 8]);
    }
    __syncthreads();
#pragma unroll
    for (int kk = 0; kk < 2; ++kk) {
      u16x8 af[4], bf[4];
#pragma unroll
      for (int m = 0; m < 4; ++m) {
        int row = wr + m * 16 + (lane & 15);
        int cs = (kk * 4 + (lane >> 4)) ^ (row & 7);
        af[m] = *reinterpret_cast<const u16x8*>(&As[row * BK + cs * 8]);
      }
#pragma unroll
      for (int n = 0; n < 4; ++n) {
        int row = wc + n * 16 + (lane & 15);
        int cs = (kk * 4 + (lane >> 4)) ^ (row & 7);
        bf[n] = *reinterpret_cast<const u16x8*>(&Bs[row * BK + cs * 8]);
      }
#pragma unroll
      for (int m = 0; m < 4; ++m)
#pragma unroll
        for (int n = 0; n < 4; ++n) mfma16(acc[m][n], af[m], bf[n]);
    }
    __syncthreads();
  }
  float bias[4];
#pragma unroll
  for (int n = 0; n < 4; ++n) bias[n] = b2[e * DM + n0 + wc + n * 16 + (lane & 15)];
#pragma unroll
  for (int m = 0; m < 4; ++m) {
#pragma unroll
    for (int r = 0; r < 4; ++r) {
      int rl = wr + m * 16 + ((lane >> 4) << 2) + r;
      if (rl < nr) {
        int ts = tsl[rl];
        float g = gl[rl];
        float* orow = out + (size_t)(ts >> 1) * DM;
#pragma unroll
        for (int n = 0; n < 4; ++n) {
          int col = n0 + wc + n * 16 + (lane & 15);
          float v = g * (acc[m][n][r] + bias[n]);
          unsafeAtomicAdd(&orow[col], v);
        }
      }
    }
  }
}

extern "C" void kernel_launch(void* const* d_in, const int* in_sizes, int n_in,
                              void* d_out, int out_size, void* d_ws, size_t ws_size,
                              hipStream_t stream) {
  const float* x  = (const float*)d_in[0];
  const float* gw = (const float*)d_in[1];
  const float* w1 = (const float*)d_in[2];
  const float* b1 = (const float*)d_in[3];
  const float* w2 = (const float*)d_in[4];
  const float* b2 = (const float*)d_in[5];
  float* out = (float*)d_out;
  char* ws = (char*)d_ws;

  size_t o = 0;
  auto alloc = [&](size_t b) { size_t p = o; o += (b + 255) & ~(size_t)255; return p; };
  size_t X16  = alloc((size_t)N_TOK * DM * 2);
  size_t W1T  = alloc((size_t)NE * DH * DM * 2);
  size_t W2T  = alloc((size_t)NE * DM * DH * 2);
  size_t HB   = alloc((size_t)HROWS * DH * 2);
  size_t TOPI = alloc((size_t)N_TOK * 2 * 4);
  size_t TOPG = alloc((size_t)N_TOK * 2 * 4);
  size_t PAIR = alloc((size_t)HROWS * 4);
  size_t CUR  = alloc(NE * 64);
  size_t OFE  = alloc(64);
  size_t TE   = alloc(MAXT * 4);
  size_t TRS  = alloc(MAXT * 4);
  size_t TNR  = alloc(MAXT * 4);
  size_t NT   = alloc(64);
  (void)ws_size; (void)in_sizes; (void)n_in;

  hipMemsetAsync(out, 0, (size_t)out_size * 4, stream);

  k_prep<<<8192 + N_TOK / 4, 256, 0, stream>>>(
      x, gw, w1, w2, (u16t*)(ws + X16), (u16t*)(ws + W1T), (u16t*)(ws + W2T),
      (int*)(ws + TOPI), (float*)(ws + TOPG));
  k_scan<<<1, 1024, 0, stream>>>((int*)(ws + TOPI), (int*)(ws + OFE), (int*)(ws + CUR),
                                 (int*)(ws + TE), (int*)(ws + TRS), (int*)(ws + TNR),
                                 (int*)(ws + NT));
  k_scatter<<<N_TOK / 256, 256, 0, stream>>>((int*)(ws + TOPI), (int*)(ws + OFE),
                                             (int*)(ws + CUR), (int*)(ws + PAIR));
  k_gemm1<<<dim3(DH / BN, MAXT), 256, 0, stream>>>(
      (const u16t*)(ws + X16), (const u16t*)(ws + W1T), b1, (u16t*)(ws + HB),
      (const int*)(ws + PAIR), (const int*)(ws + TE), (const int*)(ws + TRS),
      (const int*)(ws + TNR), (const int*)(ws + NT));
  k_gemm2<<<dim3(DM / BN, MAXT), 256, 0, stream>>>(
      (const u16t*)(ws + HB), (const u16t*)(ws + W2T), b2, out,
      (const int*)(ws + PAIR), (const float*)(ws + TOPG), (const int*)(ws + TE),
      (const int*)(ws + TRS), (const int*)(ws + TNR), (const int*)(ws + NT));
}

// Round 10
// 200.325 us; speedup vs baseline: 1.4813x; 1.0499x over previous
//
#include <hip/hip_runtime.h>
#include <hip/hip_bf16.h>
#include <cstdint>
#include <cstddef>

#define N_TOK 4096
#define DM    1024
#define DH    2048
#define NE    8
#define BM    128
#define BN    128
#define BK    64
#define MAXT  80
#define TPX   (MAXT / 8)     // row-tiles owned per XCD
#define HROWS (MAXT * BM)

typedef unsigned short u16t;
typedef __attribute__((ext_vector_type(4))) float          f32x4;
typedef __attribute__((ext_vector_type(8))) unsigned short u16x8;

__device__ __forceinline__ u16t f2b(float f) {
  union { float f; unsigned u; } v; v.f = f;
  return (u16t)((v.u + 0x7FFFu + ((v.u >> 16) & 1u)) >> 16);
}

__device__ __forceinline__ void gload16(const void* g, void* l) {
  auto gp = (const __attribute__((address_space(1))) unsigned int*)(uintptr_t)g;
  auto lp = (__attribute__((address_space(3))) unsigned int*)(uintptr_t)l;
  __builtin_amdgcn_global_load_lds(gp, lp, 16, 0, 0);
}

__device__ __forceinline__ void mfma16(f32x4& c, u16x8 a, u16x8 b) {
  asm("v_mfma_f32_16x16x32_bf16 %0, %1, %2, %0" : "+v"(c) : "v"(a), "v"(b));
}

// ============ fused prologue: tr_cvt(w1) | tr_cvt(w2) | gate(+x->bf16) ============
__global__ void __launch_bounds__(256) k_prep(
    const float* __restrict__ x,  const float* __restrict__ gw,
    const float* __restrict__ w1, const float* __restrict__ w2,
    u16t* __restrict__ x16, u16t* __restrict__ w1t, u16t* __restrict__ w2t,
    int* __restrict__ topi, float* __restrict__ topg) {
  __shared__ float smem[NE * DM];
  int b = blockIdx.x;
  int tid = threadIdx.x;
  if (b < 8192) {
    const float* src; u16t* dst; int R, C, bx, by, bz;
    if (b < 4096) {
      int l = b; bz = l >> 9; int rem = l & 511;
      R = DM; C = DH; bx = rem & 31; by = rem >> 5; src = w1; dst = w1t;
    } else {
      int l = b - 4096; bz = l >> 9; int rem = l & 511;
      R = DH; C = DM; bx = rem & 15; by = rem >> 4; src = w2; dst = w2t;
    }
    float (*t)[65] = reinterpret_cast<float(*)[65]>(smem);
    const float* s = src + (size_t)bz * R * C;
    u16t* d = dst + (size_t)bz * R * C;
    int r0 = by * 64, c0 = bx * 64;
#pragma unroll
    for (int i = 0; i < 16; ++i) {
      int idx = i * 256 + tid;
      int r = idx >> 6, c = idx & 63;
      t[r][c] = s[(size_t)(r0 + r) * C + (c0 + c)];
    }
    __syncthreads();
#pragma unroll
    for (int i = 0; i < 16; ++i) {
      int idx = i * 256 + tid;
      int rr = idx >> 6, cc = idx & 63;
      d[(size_t)(c0 + rr) * R + (r0 + cc)] = f2b(t[cc][rr]);
    }
  } else {
    float* gws = smem;
#pragma unroll
    for (int i = 0; i < NE * DM / 256; ++i) gws[i * 256 + tid] = gw[i * 256 + tid];
    __syncthreads();
    int wv = tid >> 6, lane = tid & 63;
    int t = (b - 8192) * 4 + wv;
    float acc[NE];
#pragma unroll
    for (int e = 0; e < NE; ++e) acc[e] = 0.f;
    const float* xr = x + (size_t)t * DM;
    u16t* xo = x16 + (size_t)t * DM;
#pragma unroll
    for (int c = 0; c < DM / 64; ++c) {
      float xv = xr[c * 64 + lane];
      xo[c * 64 + lane] = f2b(xv);
#pragma unroll
      for (int e = 0; e < NE; ++e) acc[e] += xv * gws[e * DM + c * 64 + lane];
    }
#pragma unroll
    for (int e = 0; e < NE; ++e) {
#pragma unroll
      for (int m = 1; m < 64; m <<= 1) acc[e] += __shfl_xor(acc[e], m);
    }
    float mx = acc[0];
#pragma unroll
    for (int e = 1; e < NE; ++e) mx = fmaxf(mx, acc[e]);
    float p[NE], s = 0.f;
#pragma unroll
    for (int e = 0; e < NE; ++e) { p[e] = expf(acc[e] - mx); s += p[e]; }
    float inv = 1.f / s;
#pragma unroll
    for (int e = 0; e < NE; ++e) p[e] *= inv;
    int i1 = 0; float g1 = p[0];
#pragma unroll
    for (int e = 1; e < NE; ++e) if (p[e] > g1) { g1 = p[e]; i1 = e; }
    int i2 = -1; float g2 = -1.f;
#pragma unroll
    for (int e = 0; e < NE; ++e) if (e != i1 && p[e] > g2) { g2 = p[e]; i2 = e; }
    if (lane == 0) {
      topi[t * 2 + 0] = i1; topi[t * 2 + 1] = i2;
      topg[t * 2 + 0] = g1; topg[t * 2 + 1] = g2;
    }
  }
}

// ------- merged histogram + scan + tile table (1 block, 1024 threads) -------
__global__ void __launch_bounds__(1024) k_scan(const int* __restrict__ topi,
                                               int* __restrict__ offe,
                                               int* __restrict__ cur64,
                                               int* __restrict__ te,
                                               int* __restrict__ trs,
                                               int* __restrict__ tnr,
                                               int* __restrict__ ntiles) {
  __shared__ int hist[NE];
  int tid = threadIdx.x;
  if (tid < NE) { hist[tid] = 0; cur64[tid * 16] = 0; }
  __syncthreads();
  int lc[NE];
#pragma unroll
  for (int e = 0; e < NE; ++e) lc[e] = 0;
#pragma unroll
  for (int i = 0; i < (N_TOK * 2) / 1024; ++i) {
    int v = topi[tid * ((N_TOK * 2) / 1024) + i];
#pragma unroll
    for (int e = 0; e < NE; ++e) lc[e] += (v == e);
  }
#pragma unroll
  for (int e = 0; e < NE; ++e) {
#pragma unroll
    for (int m = 1; m < 64; m <<= 1) lc[e] += __shfl_xor(lc[e], m);
  }
  if ((tid & 63) == 0) {
#pragma unroll
    for (int e = 0; e < NE; ++e) atomicAdd(&hist[e], lc[e]);
  }
  __syncthreads();
  if (tid == 0) {
    int off = 0, nt = 0;
    for (int e = 0; e < NE; ++e) {
      offe[e] = off;
      int c = hist[e];
      for (int i = 0; i < c; i += BM) {
        te[nt] = e; trs[nt] = off + i; tnr[nt] = min(BM, c - i); ++nt;
      }
      off += c;
    }
    *ntiles = nt;
  }
}

// ------- scatter with wave-aggregated atomics, padded counters -------
__global__ void k_scatter(const int* __restrict__ topi, const int* __restrict__ offe,
                          int* __restrict__ cur64, int* __restrict__ pair) {
  int t = blockIdx.x * blockDim.x + threadIdx.x;
  int lane = threadIdx.x & 63;
#pragma unroll
  for (int s = 0; s < 2; ++s) {
    int e = topi[t * 2 + s];
    int pos = 0;
#pragma unroll
    for (int ee = 0; ee < NE; ++ee) {
      unsigned long long mask = __ballot(e == ee);
      if (e == ee) {
        int rank = __popcll(mask & ((1ull << lane) - 1ull));
        int leader = __ffsll((long long)mask) - 1;
        int base = 0;
        if (lane == leader) base = atomicAdd(&cur64[ee * 16], (int)__popcll(mask));
        base = __shfl(base, leader);
        pos = offe[ee] + base + rank;
      }
    }
    pair[pos] = t * 2 + s;
  }
}

// -------- GEMM1: R9-exact body, XCD row-band mapping (ty-fastest within XCD) --------
// 1D grid 16*MAXT. xcd=b&7 owns ty in [xcd*TPX, xcd*TPX+TPX); inner: ty fastest ->
// consecutive same-XCD blocks share the B col-panel (L2-hot) and sweep the A band.
__global__ void __launch_bounds__(256, 2) k_gemm1(
    const u16t* __restrict__ x16, const u16t* __restrict__ w1t,
    const float* __restrict__ b1, u16t* __restrict__ h16,
    const int* __restrict__ pair, const int* __restrict__ te,
    const int* __restrict__ trs, const int* __restrict__ tnr,
    const int* __restrict__ ntiles) {
  int b = blockIdx.x;
  int ty = (b & 7) * TPX + ((b >> 3) % TPX);
  int n0 = ((b >> 3) / TPX) * BN;
  if (ty >= *ntiles) return;
  int e = te[ty], rs = trs[ty], nr = tnr[ty];
  __shared__ u16t As[BM * BK];
  __shared__ u16t Bs[BN * BK];
  __shared__ int tok[BM];
  int tid = threadIdx.x;
  if (tid < BM) {
    int p = rs + (tid < nr ? tid : nr - 1);
    tok[tid] = pair[p] >> 1;
  }
  __syncthreads();
  const u16t* aptr[4]; const u16t* bptr[4];
#pragma unroll
  for (int it = 0; it < 4; ++it) {
    int idx = it * 256 + tid;
    int r = idx >> 3, c = idx & 7;
    int cs = c ^ (r & 7);
    aptr[it] = x16 + (size_t)tok[r] * DM + cs * 8;
    bptr[it] = w1t + (size_t)e * DH * DM + (size_t)(n0 + r) * DM + cs * 8;
  }
  f32x4 acc[4][4];
#pragma unroll
  for (int m = 0; m < 4; ++m)
#pragma unroll
    for (int n = 0; n < 4; ++n) acc[m][n] = {0.f, 0.f, 0.f, 0.f};
  int lane = tid & 63, wv = tid >> 6;
  int wr = (wv >> 1) * 64, wc = (wv & 1) * 64;
  for (int k0 = 0; k0 < DM; k0 += BK) {
#pragma unroll
    for (int it = 0; it < 4; ++it) {
      int idx = it * 256 + tid;
      gload16(aptr[it] + k0, &As[idx * 8]);
      gload16(bptr[it] + k0, &Bs[idx * 8]);
    }
    __syncthreads();
#pragma unroll
    for (int kk = 0; kk < 2; ++kk) {
      u16x8 af[4], bf[4];
#pragma unroll
      for (int m = 0; m < 4; ++m) {
        int row = wr + m * 16 + (lane & 15);
        int cs = (kk * 4 + (lane >> 4)) ^ (row & 7);
        af[m] = *reinterpret_cast<const u16x8*>(&As[row * BK + cs * 8]);
      }
#pragma unroll
      for (int n = 0; n < 4; ++n) {
        int row = wc + n * 16 + (lane & 15);
        int cs = (kk * 4 + (lane >> 4)) ^ (row & 7);
        bf[n] = *reinterpret_cast<const u16x8*>(&Bs[row * BK + cs * 8]);
      }
#pragma unroll
      for (int m = 0; m < 4; ++m)
#pragma unroll
        for (int n = 0; n < 4; ++n) mfma16(acc[m][n], af[m], bf[n]);
    }
    __syncthreads();
  }
#pragma unroll
  for (int n = 0; n < 4; ++n) {
    int col = n0 + wc + n * 16 + (lane & 15);
    float bias = b1[e * DH + col];
#pragma unroll
    for (int m = 0; m < 4; ++m) {
#pragma unroll
      for (int r = 0; r < 4; ++r) {
        int rl = wr + m * 16 + ((lane >> 4) << 2) + r;
        if (rl < nr) {
          float z = acc[m][n][r] + bias;
          float g = 0.5f * z * (1.0f + erff(z * 0.70710678118654752440f));
          h16[(size_t)(rs + rl) * DH + col] = f2b(g);
        }
      }
    }
  }
}

// -------- GEMM2: R9-exact body, XCD row-band mapping --------
__global__ void __launch_bounds__(256, 2) k_gemm2(
    const u16t* __restrict__ h16, const u16t* __restrict__ w2t,
    const float* __restrict__ b2, float* __restrict__ out,
    const int* __restrict__ pair, const float* __restrict__ topg,
    const int* __restrict__ te, const int* __restrict__ trs,
    const int* __restrict__ tnr, const int* __restrict__ ntiles) {
  int b = blockIdx.x;
  int ty = (b & 7) * TPX + ((b >> 3) % TPX);
  int n0 = ((b >> 3) / TPX) * BN;
  if (ty >= *ntiles) return;
  int e = te[ty], rs = trs[ty], nr = tnr[ty];
  __shared__ u16t As[BM * BK];
  __shared__ u16t Bs[BN * BK];
  __shared__ int tsl[BM];
  __shared__ float gl[BM];
  int tid = threadIdx.x;
  if (tid < BM) {
    int p = rs + (tid < nr ? tid : nr - 1);
    int ts = pair[p];
    tsl[tid] = ts;
    gl[tid] = topg[ts];
  }
  __syncthreads();
  const u16t* aptr[4]; const u16t* bptr[4];
#pragma unroll
  for (int it = 0; it < 4; ++it) {
    int idx = it * 256 + tid;
    int r = idx >> 3, c = idx & 7;
    int cs = c ^ (r & 7);
    aptr[it] = h16 + (size_t)(rs + r) * DH + cs * 8;
    bptr[it] = w2t + (size_t)e * DM * DH + (size_t)(n0 + r) * DH + cs * 8;
  }
  f32x4 acc[4][4];
#pragma unroll
  for (int m = 0; m < 4; ++m)
#pragma unroll
    for (int n = 0; n < 4; ++n) acc[m][n] = {0.f, 0.f, 0.f, 0.f};
  int lane = tid & 63, wv = tid >> 6;
  int wr = (wv >> 1) * 64, wc = (wv & 1) * 64;
  for (int k0 = 0; k0 < DH; k0 += BK) {
#pragma unroll
    for (int it = 0; it < 4; ++it) {
      int idx = it * 256 + tid;
      gload16(aptr[it] + k0, &As[idx * 8]);
      gload16(bptr[it] + k0, &Bs[idx * 8]);
    }
    __syncthreads();
#pragma unroll
    for (int kk = 0; kk < 2; ++kk) {
      u16x8 af[4], bf[4];
#pragma unroll
      for (int m = 0; m < 4; ++m) {
        int row = wr + m * 16 + (lane & 15);
        int cs = (kk * 4 + (lane >> 4)) ^ (row & 7);
        af[m] = *reinterpret_cast<const u16x8*>(&As[row * BK + cs * 8]);
      }
#pragma unroll
      for (int n = 0; n < 4; ++n) {
        int row = wc + n * 16 + (lane & 15);
        int cs = (kk * 4 + (lane >> 4)) ^ (row & 7);
        bf[n] = *reinterpret_cast<const u16x8*>(&Bs[row * BK + cs * 8]);
      }
#pragma unroll
      for (int m = 0; m < 4; ++m)
#pragma unroll
        for (int n = 0; n < 4; ++n) mfma16(acc[m][n], af[m], bf[n]);
    }
    __syncthreads();
  }
  float bias[4];
#pragma unroll
  for (int n = 0; n < 4; ++n) bias[n] = b2[e * DM + n0 + wc + n * 16 + (lane & 15)];
#pragma unroll
  for (int m = 0; m < 4; ++m) {
#pragma unroll
    for (int r = 0; r < 4; ++r) {
      int rl = wr + m * 16 + ((lane >> 4) << 2) + r;
      if (rl < nr) {
        int ts = tsl[rl];
        float g = gl[rl];
        float* orow = out + (size_t)(ts >> 1) * DM;
#pragma unroll
        for (int n = 0; n < 4; ++n) {
          int col = n0 + wc + n * 16 + (lane & 15);
          float v = g * (acc[m][n][r] + bias[n]);
          unsafeAtomicAdd(&orow[col], v);
        }
      }
    }
  }
}

extern "C" void kernel_launch(void* const* d_in, const int* in_sizes, int n_in,
                              void* d_out, int out_size, void* d_ws, size_t ws_size,
                              hipStream_t stream) {
  const float* x  = (const float*)d_in[0];
  const float* gw = (const float*)d_in[1];
  const float* w1 = (const float*)d_in[2];
  const float* b1 = (const float*)d_in[3];
  const float* w2 = (const float*)d_in[4];
  const float* b2 = (const float*)d_in[5];
  float* out = (float*)d_out;
  char* ws = (char*)d_ws;

  size_t o = 0;
  auto alloc = [&](size_t b) { size_t p = o; o += (b + 255) & ~(size_t)255; return p; };
  size_t X16  = alloc((size_t)N_TOK * DM * 2);
  size_t W1T  = alloc((size_t)NE * DH * DM * 2);
  size_t W2T  = alloc((size_t)NE * DM * DH * 2);
  size_t HB   = alloc((size_t)HROWS * DH * 2);
  size_t TOPI = alloc((size_t)N_TOK * 2 * 4);
  size_t TOPG = alloc((size_t)N_TOK * 2 * 4);
  size_t PAIR = alloc((size_t)HROWS * 4);
  size_t CUR  = alloc(NE * 64);
  size_t OFE  = alloc(64);
  size_t TE   = alloc(MAXT * 4);
  size_t TRS  = alloc(MAXT * 4);
  size_t TNR  = alloc(MAXT * 4);
  size_t NT   = alloc(64);
  (void)ws_size; (void)in_sizes; (void)n_in;

  hipMemsetAsync(out, 0, (size_t)out_size * 4, stream);

  k_prep<<<8192 + N_TOK / 4, 256, 0, stream>>>(
      x, gw, w1, w2, (u16t*)(ws + X16), (u16t*)(ws + W1T), (u16t*)(ws + W2T),
      (int*)(ws + TOPI), (float*)(ws + TOPG));
  k_scan<<<1, 1024, 0, stream>>>((int*)(ws + TOPI), (int*)(ws + OFE), (int*)(ws + CUR),
                                 (int*)(ws + TE), (int*)(ws + TRS), (int*)(ws + TNR),
                                 (int*)(ws + NT));
  k_scatter<<<N_TOK / 256, 256, 0, stream>>>((int*)(ws + TOPI), (int*)(ws + OFE),
                                             (int*)(ws + CUR), (int*)(ws + PAIR));
  k_gemm1<<<(DH / BN) * MAXT, 256, 0, stream>>>(
      (const u16t*)(ws + X16), (const u16t*)(ws + W1T), b1, (u16t*)(ws + HB),
      (const int*)(ws + PAIR), (const int*)(ws + TE), (const int*)(ws + TRS),
      (const int*)(ws + TNR), (const int*)(ws + NT));
  k_gemm2<<<(DM / BN) * MAXT, 256, 0, stream>>>(
      (const u16t*)(ws + HB), (const u16t*)(ws + W2T), b2, out,
      (const int*)(ws + PAIR), (const float*)(ws + TOPG), (const int*)(ws + TE),
      (const int*)(ws + TRS), (const int*)(ws + TNR), (const int*)(ws + NT));
}